// Round 10
// baseline (191.382 us; speedup 1.0000x reference)
//
#include <hip/hip_runtime.h>
#include <math.h>

#define NN 512   // set size / rows of feat_x
#define IN 512   // INPUT_DIM
#define HD 256   // HIDDEN_DIM
#define RD 256   // REP_DIM
#define SH 128   // SCORE_HIDDEN

// Branchless erf-GELU, Abramowitz-Stegun 7.1.26 (|erf err| <= 1.5e-7).
__device__ __forceinline__ float gelu_fast(float x){
    const float z  = x * 0.70710678118654752f;
    const float az = fabsf(z);
    const float t  = __builtin_amdgcn_rcpf(fmaf(0.3275911f, az, 1.0f));
    float p = fmaf(1.061405429f, t, -1.453152027f);
    p = fmaf(p, t, 1.421413741f);
    p = fmaf(p, t, -0.284496736f);
    p = fmaf(p, t, 0.254829592f);
    p = p * t;
    const float e = __builtin_amdgcn_exp2f(z * z * -1.4426950408889634f);
    const float E = p * e;                        // erfc(|z|)
    const float one_plus_erf = (x >= 0.0f) ? (2.0f - E) : E;
    return 0.5f * x * one_plus_erf;
}

// u*(1+erf(u/sqrt2)) -- the 0.5 is folded into the caller's weight.
__device__ __forceinline__ float gelu2(float u){
    const float az = fabsf(u);
    const float tt = __builtin_amdgcn_rcpf(fmaf(0.23166045f, az, 1.0f));
    float p = fmaf(1.061405429f, tt, -1.453152027f);
    p = fmaf(p, tt, 1.421413741f);
    p = fmaf(p, tt, -0.284496736f);
    p = fmaf(p, tt, 0.254829592f);
    p = p * tt;
    const float e2 = __builtin_amdgcn_exp2f(u * u * -0.72134752044448170f);
    const float Eq = p * e2;                      // erfc(|u|/sqrt2)
    const float ope = (u >= 0.0f) ? (2.0f - Eq) : Eq;
    return u * ope;
}

// K_REP8: fused g-MLP + score-net projections. 192 blocks (3 mats x 64
// 8-row groups) x 256 thr = <=1 block/CU, perfectly balanced. The x operand
// is read with wave-uniform global addressing (s_load + SGPR-operand FMA,
// zero LDS). h/rloc packed [c][8] so each K-step is 2 ds_read_b128.
__global__ __launch_bounds__(256) void k_rep8(
    const float* __restrict__ fx, const float* __restrict__ fp, const float* __restrict__ fn,
    const float* __restrict__ w1, const float* __restrict__ b1,
    const float* __restrict__ w2, const float* __restrict__ b2,
    const float* __restrict__ s_w1,
    float* __restrict__ r_x, float* __restrict__ r_p, float* __restrict__ r_n,
    float* __restrict__ rT_p, float* __restrict__ rT_n,
    float* __restrict__ A_x, float* __restrict__ BT_p, float* __restrict__ BT_n)
{
    __shared__ float ps[2][8][256];   // 16 KB K-slice partials (reused as psf)
    __shared__ float hsT[256][8];     // 8 KB hidden, packed per-column
    __shared__ float rlocT[256][8];   // 8 KB rep, packed per-column
    const int t = threadIdx.x;
    const int mat = blockIdx.x >> 6;
    const int row0 = (blockIdx.x & 63) << 3;
    const float* src = (mat==0) ? fx : (mat==1) ? fp : fn;

    const int cg = t & 127, ks = t >> 7;   // 128 float2-colgroups x 2 K-slices
    const int c0 = cg << 1;

    {   // GEMM1: K=512 in 2 slices of 256; x via uniform s_load
        float2 a[8];
        #pragma unroll
        for (int j=0;j<8;j++) a[j] = make_float2(0.f,0.f);
        const float* wp = w1 + (ks << 8)*HD + c0;
        const float* xb = src + row0*IN + (ks << 8);
        #pragma unroll 8
        for (int ii=0; ii<256; ii++){
            const float2 w = *(const float2*)wp; wp += HD;
            #pragma unroll
            for (int j=0;j<8;j++){
                const float xv = xb[j*IN + ii];   // wave-uniform -> SGPR
                a[j].x = fmaf(xv, w.x, a[j].x);
                a[j].y = fmaf(xv, w.y, a[j].y);
            }
        }
        #pragma unroll
        for (int j=0;j<8;j++) *(float2*)&ps[ks][j][c0] = a[j];
    }
    __syncthreads();

    #pragma unroll
    for (int rep=0; rep<8; rep++){   // reduce + bias + GELU -> hsT
        const int idx = rep*256 + t;
        const int j = idx >> 8, c = idx & 255;
        const float v = b1[c] + ps[0][j][c] + ps[1][j][c];
        hsT[c][j] = gelu_fast(v);
    }
    __syncthreads();

    {   // GEMM2: K=256 in 2 slices of 128; h via b128 broadcasts
        float2 a[8];
        #pragma unroll
        for (int j=0;j<8;j++) a[j] = make_float2(0.f,0.f);
        const float* wp = w2 + (ks << 7)*RD + c0;
        #pragma unroll 8
        for (int ii=0; ii<128; ii++){
            const float2 w = *(const float2*)wp; wp += RD;
            const int i = (ks << 7) + ii;
            const float4 h0 = *(const float4*)&hsT[i][0];
            const float4 h1 = *(const float4*)&hsT[i][4];
            a[0].x = fmaf(h0.x, w.x, a[0].x); a[0].y = fmaf(h0.x, w.y, a[0].y);
            a[1].x = fmaf(h0.y, w.x, a[1].x); a[1].y = fmaf(h0.y, w.y, a[1].y);
            a[2].x = fmaf(h0.z, w.x, a[2].x); a[2].y = fmaf(h0.z, w.y, a[2].y);
            a[3].x = fmaf(h0.w, w.x, a[3].x); a[3].y = fmaf(h0.w, w.y, a[3].y);
            a[4].x = fmaf(h1.x, w.x, a[4].x); a[4].y = fmaf(h1.x, w.y, a[4].y);
            a[5].x = fmaf(h1.y, w.x, a[5].x); a[5].y = fmaf(h1.y, w.y, a[5].y);
            a[6].x = fmaf(h1.z, w.x, a[6].x); a[6].y = fmaf(h1.z, w.y, a[6].y);
            a[7].x = fmaf(h1.w, w.x, a[7].x); a[7].y = fmaf(h1.w, w.y, a[7].y);
        }
        #pragma unroll
        for (int j=0;j<8;j++) *(float2*)&ps[ks][j][c0] = a[j];
    }
    __syncthreads();

    {   // reduce + bias -> global r (coalesced), rT (scatter), rlocT
        float* rout = (mat==0) ? r_x : (mat==1) ? r_p : r_n;
        float* rT   = (mat==1) ? rT_p : rT_n;
        #pragma unroll
        for (int rep=0; rep<8; rep++){
            const int idx = rep*256 + t;
            const int j = idx >> 8, c = idx & 255;
            const float v = b2[c] + ps[0][j][c] + ps[1][j][c];
            rout[(row0+j)*RD + c] = v;
            rlocT[c][j] = v;
            if (mat) rT[c*NN + row0 + j] = v;
        }
    }
    __syncthreads();

    float* psf = &ps[0][0][0];   // reuse as [4][8][128]
    {   // score-net projection: 128 cols, K=256 in 4 slices of 64
        const int cg2 = t & 63, ks2 = t >> 6;
        const int cc0 = cg2 << 1;
        const float sgn = (mat==0) ? -1.0f : 1.0f;
        const int base1 = (mat==0) ? 0 : 256;
        const float* p1 = s_w1 + (base1 + (ks2 << 6))*SH + cc0;
        const float* p3 = s_w1 + (512   + (ks2 << 6))*SH + cc0;
        float2 a[8];
        #pragma unroll
        for (int j=0;j<8;j++) a[j] = make_float2(0.f,0.f);
        #pragma unroll 8
        for (int ii=0; ii<64; ii++){
            const float2 wa = *(const float2*)p1; p1 += SH;
            const float2 wd = *(const float2*)p3; p3 += SH;
            const float2 w = make_float2(fmaf(sgn, wd.x, wa.x), fmaf(sgn, wd.y, wa.y));
            const int i = (ks2 << 6) + ii;
            const float4 r0 = *(const float4*)&rlocT[i][0];
            const float4 r1 = *(const float4*)&rlocT[i][4];
            a[0].x = fmaf(r0.x, w.x, a[0].x); a[0].y = fmaf(r0.x, w.y, a[0].y);
            a[1].x = fmaf(r0.y, w.x, a[1].x); a[1].y = fmaf(r0.y, w.y, a[1].y);
            a[2].x = fmaf(r0.z, w.x, a[2].x); a[2].y = fmaf(r0.z, w.y, a[2].y);
            a[3].x = fmaf(r0.w, w.x, a[3].x); a[3].y = fmaf(r0.w, w.y, a[3].y);
            a[4].x = fmaf(r1.x, w.x, a[4].x); a[4].y = fmaf(r1.x, w.y, a[4].y);
            a[5].x = fmaf(r1.y, w.x, a[5].x); a[5].y = fmaf(r1.y, w.y, a[5].y);
            a[6].x = fmaf(r1.z, w.x, a[6].x); a[6].y = fmaf(r1.z, w.y, a[6].y);
            a[7].x = fmaf(r1.w, w.x, a[7].x); a[7].y = fmaf(r1.w, w.y, a[7].y);
        }
        #pragma unroll
        for (int j=0;j<8;j++) *(float2*)&psf[((ks2 << 3) + j)*SH + cc0] = a[j];
    }
    __syncthreads();

    #pragma unroll
    for (int rep=0; rep<4; rep++){   // reduce 4 slices; A coalesced / BT scatter
        const int idx = rep*256 + t;
        const int j = idx >> 7, c = idx & 127;
        const float v = psf[j*SH+c] + psf[(8+j)*SH+c] + psf[(16+j)*SH+c] + psf[(24+j)*SH+c];
        if (mat==0) A_x[(row0+j)*SH + c] = v;
        else        ((mat==1) ? BT_p : BT_n)[c*NN + row0 + j] = v;
    }
}

// K_SD: verbatim round-9 version (46.7 us, conflict-free, wave-level k-split).
__global__ __launch_bounds__(256) void k_sd(
    const float* __restrict__ r_x, const float* __restrict__ rT_p, const float* __restrict__ rT_n,
    const float* __restrict__ A_x, const float* __restrict__ BT_p, const float* __restrict__ BT_n,
    const float* __restrict__ s_w1, const float* __restrict__ s_b1,
    const float* __restrict__ s_w2,
    float* __restrict__ E_p, float* __restrict__ E_n, float* __restrict__ Spart)
{
    __shared__ float2 xs2[RD];
    __shared__ float4 cmb[SH];
    __shared__ float pda[2][128];
    __shared__ float pdb[2][128];
    __shared__ float pdc[2][128];
    __shared__ float nx[2];
    __shared__ float ssum[2][2];
    const int t = threadIdx.x;
    const int set = blockIdx.x >> 10;
    const int rem = blockIdx.x & 1023;
    const int n0 = (rem >> 2) << 1;
    const int mt = rem & 3;
    const int mbase = mt << 7;
    const int tm = t & 127, kh = t >> 7;
    const int m = mbase + tm;
    const float* yT = set ? rT_n : rT_p;
    const float* BT = set ? BT_n : BT_p;
    float* E = set ? E_n : E_p;

    xs2[t] = make_float2(r_x[n0*RD + t], r_x[(n0+1)*RD + t]);
    if (t < SH){
        const float b1v = s_b1[t];
        cmb[t] = make_float4(A_x[n0*SH + t] + b1v,
                             A_x[(n0+1)*SH + t] + b1v,
                             s_w1[768*SH + t],
                             0.5f * s_w2[t]);
    }
    __syncthreads();

    if (t < 128){
        const int w = t >> 6, l = t & 63;
        float v = 0.f;
        #pragma unroll
        for (int q=0;q<4;q++){
            const float2 e = xs2[l + 64*q];
            const float ev = w ? e.y : e.x;
            v = fmaf(ev, ev, v);
        }
        #pragma unroll
        for (int off=32; off>=1; off>>=1) v += __shfl_xor(v, off);
        if (l==0) nx[w] = v;
    }

    float d0=0.f, d1=0.f, ny=0.f;
    {
        const float* yp = yT + (kh << 7)*NN + m;
        #pragma unroll 16
        for (int rr=0; rr<128; rr++){
            const float y = yp[rr*NN];
            const float2 xv = xs2[(kh << 7) + rr];
            d0 = fmaf(xv.x, y, d0);
            d1 = fmaf(xv.y, y, d1);
            ny = fmaf(y, y, ny);
        }
    }
    pda[kh][tm] = d0; pdb[kh][tm] = d1; pdc[kh][tm] = ny;
    __syncthreads();
    d0 += pda[1-kh][tm]; d1 += pdb[1-kh][tm]; ny += pdc[1-kh][tm];
    const float dn0 = sqrtf(fmaxf(fmaf(-2.f, d0, nx[0] + ny), 0.f));
    const float dn1 = sqrtf(fmaxf(fmaf(-2.f, d1, nx[1] + ny), 0.f));

    float acc0 = 0.f, acc1 = 0.f;
    {
        const float* bp = BT + (kh << 6)*NN + m;
        #pragma unroll 4
        for (int kk=0; kk<64; kk++){
            const float b = bp[kk*NN];
            const float4 c = cmb[(kh << 6) + kk];
            const float u0 = fmaf(dn0, c.z, c.x + b);
            const float u1 = fmaf(dn1, c.z, c.y + b);
            acc0 = fmaf(c.w, gelu2(u0), acc0);
            acc1 = fmaf(c.w, gelu2(u1), acc1);
        }
    }
    __syncthreads();
    pda[kh][tm] = acc0; pdb[kh][tm] = acc1;
    __syncthreads();
    if (kh == 0){
        const float ev0 = __builtin_amdgcn_exp2f((acc0 + pda[1][tm]) * 1.4426950408889634f);
        const float ev1 = __builtin_amdgcn_exp2f((acc1 + pdb[1][tm]) * 1.4426950408889634f);
        E[n0*NN + m]     = ev0;
        E[(n0+1)*NN + m] = ev1;
        float v0 = ev0, v1 = ev1;
        #pragma unroll
        for (int off=32; off>=1; off>>=1){ v0 += __shfl_xor(v0, off); v1 += __shfl_xor(v1, off); }
        if ((t & 63) == 0){
            ssum[tm >> 6][0] = v0;
            ssum[tm >> 6][1] = v1;
        }
    }
    __syncthreads();
    if (t < 2)
        Spart[(set*4 + mt)*NN + n0 + t] = ssum[0][t] + ssum[1][t];
}

// K_DV: partial einsum over a 64-m slice, both sets combined (pos - neg).
// 1024 blocks (128 4-row ntiles x 8 m-slices). psum[ms][n][c].
__global__ __launch_bounds__(256) void k_dv(
    const float* __restrict__ E_p, const float* __restrict__ E_n,
    const float* __restrict__ Spart,
    const float* __restrict__ r_p, const float* __restrict__ r_n,
    float* __restrict__ psum)
{
    __shared__ float rinv[8];
    __shared__ float wbuf[2][64][4];
    const int t = threadIdx.x;
    const int nt = blockIdx.x >> 3;
    const int ms = blockIdx.x & 7;
    const int n0 = nt << 2, mbase = ms << 6;

    if (t < 8){
        const int se = t >> 2, n = n0 + (t & 3);
        float S = 0.f;
        #pragma unroll
        for (int q=0;q<4;q++) S += Spart[(se*4+q)*NN + n];
        rinv[t] = 1.0f / S;
    }
    __syncthreads();
    #pragma unroll
    for (int rep=0; rep<2; rep++){
        const int idx = rep*256 + t;
        const int se = idx >> 8, j = (idx >> 6) & 3, mm = idx & 63;
        const float* E = se ? E_n : E_p;
        wbuf[se][mm][j] = E[(n0+j)*NN + mbase + mm] * rinv[se*4 + j];
    }
    __syncthreads();

    float acc[4] = {0.f,0.f,0.f,0.f};
    {
        const float* rp = r_p + mbase*RD + t;
        #pragma unroll 4
        for (int mm=0; mm<64; mm++){
            const float rv = *rp; rp += RD;
            const float4 wa = *(const float4*)&wbuf[0][mm][0];
            acc[0]=fmaf(wa.x,rv,acc[0]); acc[1]=fmaf(wa.y,rv,acc[1]);
            acc[2]=fmaf(wa.z,rv,acc[2]); acc[3]=fmaf(wa.w,rv,acc[3]);
        }
    }
    {
        const float* rn = r_n + mbase*RD + t;
        #pragma unroll 4
        for (int mm=0; mm<64; mm++){
            const float rv = -(*rn); rn += RD;
            const float4 wa = *(const float4*)&wbuf[1][mm][0];
            acc[0]=fmaf(wa.x,rv,acc[0]); acc[1]=fmaf(wa.y,rv,acc[1]);
            acc[2]=fmaf(wa.z,rv,acc[2]); acc[3]=fmaf(wa.w,rv,acc[3]);
        }
    }
    float* P = psum + ms*(NN*RD);
    #pragma unroll
    for (int j=0;j<4;j++) P[(n0+j)*RD + t] = acc[j];
}

// K_OUT: dv = sum_ms psum; out = dv @ out_w. 1024 blocks (256 2-row ntiles x
// 4 128-col tiles).
__global__ __launch_bounds__(256) void k_out(
    const float* __restrict__ psum, const float* __restrict__ out_w,
    float* __restrict__ out)
{
    __shared__ float dv2[2][RD];
    __shared__ float ps[2][2][128];
    const int t = threadIdx.x;
    const int nt = blockIdx.x >> 2;
    const int cb = (blockIdx.x & 3) << 7;
    const int n0 = nt << 1;

    #pragma unroll
    for (int j=0;j<2;j++){
        float v = 0.f;
        #pragma unroll
        for (int ms=0; ms<8; ms++) v += psum[ms*(NN*RD) + (n0+j)*RD + t];
        dv2[j][t] = v;
    }
    __syncthreads();

    const int cc = t & 127, s = t >> 7;
    float a0 = 0.f, a1 = 0.f;
    const float* wo = out_w + (s*128)*IN + cb + cc;
    #pragma unroll 4
    for (int rr=0; rr<128; rr++){
        const float w = *wo; wo += IN;
        a0 = fmaf(dv2[0][s*128 + rr], w, a0);
        a1 = fmaf(dv2[1][s*128 + rr], w, a1);
    }
    ps[s][0][cc] = a0;
    ps[s][1][cc] = a1;
    __syncthreads();
    {
        const int j = t >> 7, c = t & 127;
        out[(n0+j)*IN + cb + c] = ps[0][j][c] + ps[1][j][c];
    }
}

extern "C" void kernel_launch(void* const* d_in, const int* in_sizes, int n_in,
                              void* d_out, int out_size, void* d_ws, size_t ws_size,
                              hipStream_t stream)
{
    const float* fx  = (const float*)d_in[0];
    const float* fp  = (const float*)d_in[1];
    const float* fn  = (const float*)d_in[2];
    const float* gw1 = (const float*)d_in[3];
    const float* gb1 = (const float*)d_in[4];
    const float* gw2 = (const float*)d_in[5];
    const float* gb2 = (const float*)d_in[6];
    const float* ow  = (const float*)d_in[7];
    const float* sw1 = (const float*)d_in[8];
    const float* sb1 = (const float*)d_in[9];
    const float* sw2 = (const float*)d_in[10];
    float* out = (float*)d_out;

    float* ws   = (float*)d_ws;
    float* r_x  = ws;               // 512*256 row-major
    float* r_p  = r_x  + 131072;
    float* r_n  = r_p  + 131072;
    float* rT_p = r_n  + 131072;    // 256*512 column-major
    float* rT_n = rT_p + 131072;
    float* A_x  = rT_n + 131072;    // 512*128 row-major [n][k]
    float* BT_p = A_x  + 65536;     // 128*512 column-major [k][m]
    float* BT_n = BT_p + 65536;
    float* E_p  = BT_n + 65536;     // 512*512
    float* E_n  = E_p  + 262144;
    float* Spar = E_n  + 262144;    // 2*4*512
    float* psum = Spar + 4096;      // 8*512*256 (4 MB)

    hipLaunchKernelGGL(k_rep8, dim3(192), dim3(256), 0, stream,
                       fx, fp, fn, gw1, gb1, gw2, gb2, sw1,
                       r_x, r_p, r_n, rT_p, rT_n, A_x, BT_p, BT_n);
    hipLaunchKernelGGL(k_sd, dim3(2048), dim3(256), 0, stream,
                       r_x, rT_p, rT_n, A_x, BT_p, BT_n,
                       sw1, sb1, sw2, E_p, E_n, Spar);
    hipLaunchKernelGGL(k_dv, dim3(1024), dim3(256), 0, stream,
                       E_p, E_n, Spar, r_p, r_n, psum);
    hipLaunchKernelGGL(k_out, dim3(1024), dim3(256), 0, stream,
                       psum, ow, out);
}

// Round 12
// 159.339 us; speedup vs baseline: 1.2011x; 1.2011x over previous
//
#include <hip/hip_runtime.h>
#include <math.h>

#define NN 512   // set size / rows of feat_x
#define IN 512   // INPUT_DIM
#define HD 256   // HIDDEN_DIM
#define RD 256   // REP_DIM
#define SH 128   // SCORE_HIDDEN

// Branchless erf-GELU, Abramowitz-Stegun 7.1.26 (|erf err| <= 1.5e-7).
__device__ __forceinline__ float gelu_fast(float x){
    const float z  = x * 0.70710678118654752f;
    const float az = fabsf(z);
    const float t  = __builtin_amdgcn_rcpf(fmaf(0.3275911f, az, 1.0f));
    float p = fmaf(1.061405429f, t, -1.453152027f);
    p = fmaf(p, t, 1.421413741f);
    p = fmaf(p, t, -0.284496736f);
    p = fmaf(p, t, 0.254829592f);
    p = p * t;
    const float e = __builtin_amdgcn_exp2f(z * z * -1.4426950408889634f);
    const float E = p * e;                        // erfc(|z|)
    const float one_plus_erf = (x >= 0.0f) ? (2.0f - E) : E;
    return 0.5f * x * one_plus_erf;
}

// u*(1+erf(u/sqrt2)) -- the 0.5 is folded into the caller's weight.
__device__ __forceinline__ float gelu2(float u){
    const float az = fabsf(u);
    const float tt = __builtin_amdgcn_rcpf(fmaf(0.23166045f, az, 1.0f));
    float p = fmaf(1.061405429f, tt, -1.453152027f);
    p = fmaf(p, tt, 1.421413741f);
    p = fmaf(p, tt, -0.284496736f);
    p = fmaf(p, tt, 0.254829592f);
    p = p * tt;
    const float e2 = __builtin_amdgcn_exp2f(u * u * -0.72134752044448170f);
    const float Eq = p * e2;                      // erfc(|u|/sqrt2)
    const float ope = (u >= 0.0f) ? (2.0f - Eq) : Eq;
    return u * ope;
}

// K_REP: fused g-MLP + score-net projections (round-6 proven body).
// 384 blocks (3 mats x 128 4-row groups) x 512 threads = 8 waves/block,
// 12 waves/CU at 1.5 blocks/CU. h and rep stay in LDS.
__global__ __launch_bounds__(512) void k_rep(
    const float* __restrict__ fx, const float* __restrict__ fp, const float* __restrict__ fn,
    const float* __restrict__ w1, const float* __restrict__ b1,
    const float* __restrict__ w2, const float* __restrict__ b2,
    const float* __restrict__ s_w1,
    float* __restrict__ r_x, float* __restrict__ r_p, float* __restrict__ r_n,
    float* __restrict__ rT_p, float* __restrict__ rT_n,
    float* __restrict__ A_x, float* __restrict__ BT_p, float* __restrict__ BT_n)
{
    __shared__ float xs[4][IN];        // 8 KB
    __shared__ float ps[8][4][HD];     // 32 KB partials (reused by all GEMM phases)
    __shared__ float hs[4][HD];        // 4 KB
    __shared__ float rloc[4][RD];      // 4 KB
    __shared__ float ab4[4][SH];       // 2 KB
    const int t = threadIdx.x;
    const int mat = blockIdx.x >> 7;
    const int row0 = (blockIdx.x & 127) << 2;
    const float* src = (mat==0) ? fx : (mat==1) ? fp : fn;

    {   // stage 4 feat rows: 512 float4s
        const int j = t >> 7, c4 = (t & 127) << 2;
        *(float4*)&xs[j][c4] = *(const float4*)&src[(row0+j)*IN + c4];
    }
    __syncthreads();

    const int cg = t & 63, s = t >> 6;   // 64 colgroups x 8 K-slices
    const int c0 = cg << 2;

    {   // GEMM1: K=512, slice [s*64, s*64+64)
        float4 acc[4];
        #pragma unroll
        for (int j=0;j<4;j++) acc[j] = make_float4(0.f,0.f,0.f,0.f);
        const float* wp = w1 + (s*64)*HD + c0;
        #pragma unroll 8
        for (int ii=0; ii<64; ii++){
            float4 w = *(const float4*)wp; wp += HD;
            const int i = s*64 + ii;
            #pragma unroll
            for (int j=0;j<4;j++){
                const float xv = xs[j][i];
                acc[j].x = fmaf(xv, w.x, acc[j].x);
                acc[j].y = fmaf(xv, w.y, acc[j].y);
                acc[j].z = fmaf(xv, w.z, acc[j].z);
                acc[j].w = fmaf(xv, w.w, acc[j].w);
            }
        }
        #pragma unroll
        for (int j=0;j<4;j++) *(float4*)&ps[s][j][c0] = acc[j];
    }
    __syncthreads();

    #pragma unroll
    for (int rep=0; rep<2; rep++){   // reduce + bias + GELU -> hs
        const int idx = rep*512 + t;
        const int j = idx >> 8, c = idx & 255;
        float v = b1[c];
        #pragma unroll
        for (int ss=0; ss<8; ss++) v += ps[ss][j][c];
        hs[j][c] = gelu_fast(v);
    }
    __syncthreads();

    {   // GEMM2: K=256, slice [s*32, s*32+32)
        float4 acc[4];
        #pragma unroll
        for (int j=0;j<4;j++) acc[j] = make_float4(0.f,0.f,0.f,0.f);
        const float* wp = w2 + (s*32)*RD + c0;
        #pragma unroll 8
        for (int ii=0; ii<32; ii++){
            float4 w = *(const float4*)wp; wp += RD;
            const int i = s*32 + ii;
            #pragma unroll
            for (int j=0;j<4;j++){
                const float xv = hs[j][i];
                acc[j].x = fmaf(xv, w.x, acc[j].x);
                acc[j].y = fmaf(xv, w.y, acc[j].y);
                acc[j].z = fmaf(xv, w.z, acc[j].z);
                acc[j].w = fmaf(xv, w.w, acc[j].w);
            }
        }
        #pragma unroll
        for (int j=0;j<4;j++) *(float4*)&ps[s][j][c0] = acc[j];
    }
    __syncthreads();

    float* rout = (mat==0) ? r_x : (mat==1) ? r_p : r_n;
    #pragma unroll
    for (int rep=0; rep<2; rep++){   // reduce + bias -> rloc + global r
        const int idx = rep*512 + t;
        const int j = idx >> 8, c = idx & 255;
        float v = b2[c];
        #pragma unroll
        for (int ss=0; ss<8; ss++) v += ps[ss][j][c];
        rloc[j][c] = v;
        rout[(row0+j)*RD + c] = v;
    }
    __syncthreads();   // rloc complete; ps free for reuse

    if (mat && t < 256){   // transposed rep copy rT[r][m], float4 across rows
        float* rT = (mat==1) ? rT_p : rT_n;
        float4 q = make_float4(rloc[0][t], rloc[1][t], rloc[2][t], rloc[3][t]);
        *(float4*)&rT[t*NN + row0] = q;
    }

    {   // score-net projection: 128 cols, K=256 in 16 slices of 16
        const int cg2 = t & 31, s2 = t >> 5;
        const int cc0 = cg2 << 2;
        const float sgn = (mat==0) ? -1.0f : 1.0f;
        const int base1 = (mat==0) ? 0 : 256;
        const float* p1 = s_w1 + (base1 + s2*16)*SH + cc0;
        const float* p3 = s_w1 + (512   + s2*16)*SH + cc0;
        float4 a[4];
        #pragma unroll
        for (int j=0;j<4;j++) a[j] = make_float4(0.f,0.f,0.f,0.f);
        #pragma unroll 8
        for (int ii=0; ii<16; ii++){
            float4 wa = *(const float4*)p1; p1 += SH;
            float4 wd = *(const float4*)p3; p3 += SH;
            float4 w;
            w.x = fmaf(sgn, wd.x, wa.x);
            w.y = fmaf(sgn, wd.y, wa.y);
            w.z = fmaf(sgn, wd.z, wa.z);
            w.w = fmaf(sgn, wd.w, wa.w);
            const int i = s2*16 + ii;
            #pragma unroll
            for (int j=0;j<4;j++){
                const float xv = rloc[j][i];
                a[j].x = fmaf(xv, w.x, a[j].x);
                a[j].y = fmaf(xv, w.y, a[j].y);
                a[j].z = fmaf(xv, w.z, a[j].z);
                a[j].w = fmaf(xv, w.w, a[j].w);
            }
        }
        float* psf = &ps[0][0][0];   // reuse as [16][4][128]
        #pragma unroll
        for (int j=0;j<4;j++) *(float4*)&psf[(s2*4 + j)*SH + cc0] = a[j];
    }
    __syncthreads();

    {   // reduce 16 slices: 4 rows x 128 cols = 512 outputs
        const float* psf = &ps[0][0][0];
        const int j = t >> 7, c = t & 127;
        float v = 0.f;
        #pragma unroll
        for (int ss=0; ss<16; ss++) v += psf[(ss*4 + j)*SH + c];
        if (mat==0) A_x[(row0+j)*SH + c] = v;
        else        ab4[j][c] = v;
    }
    __syncthreads();
    if (mat && t < 128){   // BT[k][m], float4 across rows
        float* BT = (mat==1) ? BT_p : BT_n;
        float4 q = make_float4(ab4[0][t], ab4[1][t], ab4[2][t], ab4[3][t]);
        *(float4*)&BT[t*NN + row0] = q;
    }
}

// K_SD: distances + logits + exp + FUSED partial einsum. 2048 blocks
// (set x 256 2-row ntiles x 4 128-m mtiles) x 256 thr = 8 blocks/CU.
// The block's 128 ev values feed Sum_m ev*r_y[m][c] directly into
// psum[set][mt][n][c] (no E matrix, no atomics; normalization deferred).
__global__ __launch_bounds__(256) void k_sd(
    const float* __restrict__ r_x, const float* __restrict__ rT_p, const float* __restrict__ rT_n,
    const float* __restrict__ A_x, const float* __restrict__ BT_p, const float* __restrict__ BT_n,
    const float* __restrict__ r_p, const float* __restrict__ r_n,
    const float* __restrict__ s_w1, const float* __restrict__ s_b1,
    const float* __restrict__ s_w2,
    float* __restrict__ psum, float* __restrict__ Spart)
{
    __shared__ float2 xs2[RD];        // 2 KB: {x0,x1}[r]
    __shared__ float4 cmb[SH];        // 2 KB: {A0+b1, A1+b1, wn, 0.5*w2}
    __shared__ float pda[2][128];     // stride-4B partials (conflict-free)
    __shared__ float pdb[2][128];
    __shared__ float pdc[2][128];
    __shared__ float2 evb[128];       // 1 KB: per-m {ev0, ev1}
    __shared__ float nx[2];
    __shared__ float ssum[2][2];
    const int t = threadIdx.x;
    const int set = blockIdx.x >> 10;
    const int rem = blockIdx.x & 1023;
    const int n0 = (rem >> 2) << 1;
    const int mt = rem & 3;
    const int mbase = mt << 7;
    const int tm = t & 127, kh = t >> 7;   // kh uniform per wave
    const int m = mbase + tm;
    const float* yT = set ? rT_n : rT_p;
    const float* BT = set ? BT_n : BT_p;

    xs2[t] = make_float2(r_x[n0*RD + t], r_x[(n0+1)*RD + t]);
    if (t < SH){
        const float b1v = s_b1[t];
        cmb[t] = make_float4(A_x[n0*SH + t] + b1v,
                             A_x[(n0+1)*SH + t] + b1v,
                             s_w1[768*SH + t],
                             0.5f * s_w2[t]);
    }
    __syncthreads();

    if (t < 128){   // x-row norms (waves 0,1 -> rows 0,1)
        const int w = t >> 6, l = t & 63;
        float v = 0.f;
        #pragma unroll
        for (int q=0;q<4;q++){
            const float2 e = xs2[l + 64*q];
            const float ev = w ? e.y : e.x;
            v = fmaf(ev, ev, v);
        }
        #pragma unroll
        for (int off=32; off>=1; off>>=1) v += __shfl_xor(v, off);
        if (l==0) nx[w] = v;
    }

    // phase 1: dots + ||y||^2 over this wave's r-half (coalesced loads)
    float d0=0.f, d1=0.f, ny=0.f;
    {
        const float* yp = yT + (kh << 7)*NN + m;
        #pragma unroll 16
        for (int rr=0; rr<128; rr++){
            const float y = yp[rr*NN];
            const float2 xv = xs2[(kh << 7) + rr];
            d0 = fmaf(xv.x, y, d0);
            d1 = fmaf(xv.y, y, d1);
            ny = fmaf(y, y, ny);
        }
    }
    pda[kh][tm] = d0; pdb[kh][tm] = d1; pdc[kh][tm] = ny;
    __syncthreads();
    d0 += pda[1-kh][tm]; d1 += pdb[1-kh][tm]; ny += pdc[1-kh][tm];
    const float dn0 = sqrtf(fmaxf(fmaf(-2.f, d0, nx[0] + ny), 0.f));
    const float dn1 = sqrtf(fmaxf(fmaf(-2.f, d1, nx[1] + ny), 0.f));

    // phase 2: logits over this wave's k-half (coalesced BT loads)
    float acc0 = 0.f, acc1 = 0.f;
    {
        const float* bp = BT + (kh << 6)*NN + m;
        #pragma unroll 4
        for (int kk=0; kk<64; kk++){
            const float b = bp[kk*NN];
            const float4 c = cmb[(kh << 6) + kk];
            const float u0 = fmaf(dn0, c.z, c.x + b);
            const float u1 = fmaf(dn1, c.z, c.y + b);
            acc0 = fmaf(c.w, gelu2(u0), acc0);
            acc1 = fmaf(c.w, gelu2(u1), acc1);
        }
    }
    __syncthreads();                       // partner done reading phase-1 pd
    pda[kh][tm] = acc0; pdb[kh][tm] = acc1;
    __syncthreads();
    if (kh == 0){
        // s_b2 omitted (softmax shift-invariant); no max pass (logits O(1))
        const float ev0 = __builtin_amdgcn_exp2f((acc0 + pda[1][tm]) * 1.4426950408889634f);
        const float ev1 = __builtin_amdgcn_exp2f((acc1 + pdb[1][tm]) * 1.4426950408889634f);
        evb[tm] = make_float2(ev0, ev1);
        float v0 = ev0, v1 = ev1;
        #pragma unroll
        for (int off=32; off>=1; off>>=1){ v0 += __shfl_xor(v0, off); v1 += __shfl_xor(v1, off); }
        if ((t & 63) == 0){
            ssum[tm >> 6][0] = v0;
            ssum[tm >> 6][1] = v1;
        }
    }
    __syncthreads();
    if (t < 2)
        Spart[(set*4 + mt)*NN + n0 + t] = ssum[0][t] + ssum[1][t];

    // fused partial einsum: psum[set][mt][n0+j][c] = Sum_{m in tile} ev_j * r_y[m][c]
    {
        const float* ry = (set ? r_n : r_p) + mbase*RD + t;   // coalesced in c=t
        float a0 = 0.f, a1 = 0.f;
        #pragma unroll 8
        for (int mm=0; mm<128; mm++){
            const float rv = ry[mm*RD];
            const float2 w = evb[mm];        // ds_read_b64 broadcast
            a0 = fmaf(w.x, rv, a0);
            a1 = fmaf(w.y, rv, a1);
        }
        float* P = psum + ((set*4 + mt)*NN + n0)*RD;
        P[t]      = a0;
        P[RD + t] = a1;
    }
}

// K_FIN: dv = Sum_mt psum_p/Sp - Sum_mt psum_n/Sn; out = dv @ out_w.
// 512 blocks (256 n-pairs x 2 col-halves) x 512 thr = 2 blocks/CU, 16 waves.
__global__ __launch_bounds__(512) void k_fin(
    const float* __restrict__ psum, const float* __restrict__ Spart,
    const float* __restrict__ out_w, float* __restrict__ out)
{
    __shared__ float dv[2][RD];   // 2 KB
    const int t = threadIdx.x;
    const int np = blockIdx.x >> 1, ch = blockIdx.x & 1;
    const int n0 = np << 1;

    {   // dv: 2 rows x 256 r, one per thread
        const int j = t >> 8, c = t & 255;
        const int n = n0 + j;
        float Sp = 0.f, Sn = 0.f;
        #pragma unroll
        for (int q=0;q<4;q++){
            Sp += Spart[q*NN + n];
            Sn += Spart[(4+q)*NN + n];
        }
        float vp = 0.f, vn = 0.f;
        #pragma unroll
        for (int q=0;q<4;q++){
            vp += psum[(q*NN + n)*RD + c];
            vn += psum[((4+q)*NN + n)*RD + c];
        }
        dv[j][c] = vp * (1.0f/Sp) - vn * (1.0f/Sn);
    }
    __syncthreads();

    {   // out[j][col] = Sum_r dv[j][r]*out_w[r][col]; col-half per block
        const int j = t >> 8, col = (ch << 8) + (t & 255);
        float o = 0.f;
        const float* wo = out_w + col;
        #pragma unroll 8
        for (int r=0; r<RD; r++){ o = fmaf(dv[j][r], *wo, o); wo += IN; }
        out[(n0+j)*IN + col] = o;
    }
}

extern "C" void kernel_launch(void* const* d_in, const int* in_sizes, int n_in,
                              void* d_out, int out_size, void* d_ws, size_t ws_size,
                              hipStream_t stream)
{
    const float* fx  = (const float*)d_in[0];
    const float* fp  = (const float*)d_in[1];
    const float* fn  = (const float*)d_in[2];
    const float* gw1 = (const float*)d_in[3];
    const float* gb1 = (const float*)d_in[4];
    const float* gw2 = (const float*)d_in[5];
    const float* gb2 = (const float*)d_in[6];
    const float* ow  = (const float*)d_in[7];
    const float* sw1 = (const float*)d_in[8];
    const float* sb1 = (const float*)d_in[9];
    const float* sw2 = (const float*)d_in[10];
    float* out = (float*)d_out;

    float* ws   = (float*)d_ws;
    float* r_x  = ws;               // 512*256 row-major
    float* r_p  = r_x  + 131072;
    float* r_n  = r_p  + 131072;
    float* rT_p = r_n  + 131072;    // 256*512 column-major
    float* rT_n = rT_p + 131072;
    float* A_x  = rT_n + 131072;    // 512*128 row-major [n][k]
    float* BT_p = A_x  + 65536;     // 128*512 column-major [k][m]
    float* BT_n = BT_p + 65536;
    float* Spar = BT_n + 65536;     // 2*4*512
    float* psum = Spar + 4096;      // 2*4*512*256 (4 MB)

    hipLaunchKernelGGL(k_rep, dim3(384), dim3(512), 0, stream,
                       fx, fp, fn, gw1, gb1, gw2, gb2, sw1,
                       r_x, r_p, r_n, rT_p, rT_n, A_x, BT_p, BT_n);
    hipLaunchKernelGGL(k_sd, dim3(2048), dim3(256), 0, stream,
                       r_x, rT_p, rT_n, A_x, BT_p, BT_n, r_p, r_n,
                       sw1, sb1, sw2, psum, Spar);
    hipLaunchKernelGGL(k_fin, dim3(512), dim3(512), 0, stream,
                       psum, Spar, ow, out);
}